// Round 1
// baseline (197.832 us; speedup 1.0000x reference)
//
#include <hip/hip_runtime.h>

typedef unsigned short u16;
typedef unsigned int   u32;
typedef short bf16x8 __attribute__((ext_vector_type(8)));
typedef float f32x4  __attribute__((ext_vector_type(4)));
typedef u16   u16x4  __attribute__((ext_vector_type(4)));
typedef u16   u16x8  __attribute__((ext_vector_type(8)));
typedef u32   u32x4  __attribute__((ext_vector_type(4)));

#define DEV __device__ __forceinline__

// ---------- helpers ----------
DEV u16 f2bf(float f) {                       // fp32 -> bf16 RNE
  u32 u = __builtin_bit_cast(u32, f);
  u32 r = (u + 0x7FFFu + ((u >> 16) & 1u)) >> 16;
  return (u16)r;
}
DEV u32 pack2(float lo, float hi) {
  return (u32)f2bf(lo) | ((u32)f2bf(hi) << 16);
}
DEV void gll16(const u16* g, u16* l) {        // async global->LDS, 16B/lane
  __builtin_amdgcn_global_load_lds((const __attribute__((address_space(1))) u32*)g,
                                   (__attribute__((address_space(3))) u32*)l,
                                   16, 0, 0);
}

// ---------- kernel 1: fp32 -> bf16 convert (vectorized, 8 elems/thread) ----------
__global__ __launch_bounds__(256)
void cvt_bf16(const float* __restrict__ in, u16* __restrict__ out, int n8) {
  int i = blockIdx.x * 256 + threadIdx.x;
  if (i >= n8) return;
  float4 a = ((const float4*)in)[2*i];
  float4 b = ((const float4*)in)[2*i+1];
  u16x8 o;
  o[0]=f2bf(a.x); o[1]=f2bf(a.y); o[2]=f2bf(a.z); o[3]=f2bf(a.w);
  o[4]=f2bf(b.x); o[5]=f2bf(b.y); o[6]=f2bf(b.z); o[7]=f2bf(b.w);
  *(u16x8*)(out + (size_t)i*8) = o;
}

// ---------- kernel 2: W [R][C] fp32 -> W^T [C][R] bf16 (64x64 LDS tile) ----------
__global__ __launch_bounds__(256)
void transpose_w(const float* __restrict__ in, u16* __restrict__ out, int R, int C) {
  __shared__ float t64[64][65];
  const int r0 = blockIdx.x*64, c0 = blockIdx.y*64;
  const int tr = threadIdx.x >> 4, tc = (threadIdx.x & 15) * 4;
  #pragma unroll
  for (int i = 0; i < 4; ++i) {
    int r = i*16 + tr;
    float4 v = *(const float4*)(in + (size_t)(r0 + r)*C + c0 + tc);
    t64[r][tc+0]=v.x; t64[r][tc+1]=v.y; t64[r][tc+2]=v.z; t64[r][tc+3]=v.w;
  }
  __syncthreads();
  #pragma unroll
  for (int i = 0; i < 4; ++i) {
    int r = i*16 + tr;                     // output row (= input col c0+r)
    u16x4 ov;
    ov[0]=f2bf(t64[tc+0][r]); ov[1]=f2bf(t64[tc+1][r]);
    ov[2]=f2bf(t64[tc+2][r]); ov[3]=f2bf(t64[tc+3][r]);
    *(u16x4*)(out + (size_t)(c0 + r)*R + r0 + tc) = ov;
  }
}

// ---------- kernel 3/7: bf16 GEMM, m97 structure (128x128 tile, BK=32) ----------
// A [M][K] bf16, Bt [N][K] bf16 (pre-transposed weights), K=768.
// MODE 0: QKV epilogue (bias + route q/k/v).  MODE 1: proj epilogue (bias + fp32 out).
template<int MODE>
__global__ __launch_bounds__(256)
void gemm_k(const u16* __restrict__ A, const u16* __restrict__ Bt,
            const float* __restrict__ bias,
            float* __restrict__ o0, float* __restrict__ o1,
            u16* __restrict__ qo, u16* __restrict__ ko)
{
  constexpr int K = 768;
  __shared__ u16 As[128*32];
  __shared__ u16 Bs[128*32];
  const int tid = threadIdx.x;
  const int w  = tid >> 6, ln = tid & 63;
  const int wr = w >> 1,  wc = w & 1;
  const int g  = ln >> 4, c  = ln & 15;
  const int tm = blockIdx.x * 128, tn = blockIdx.y * 128;

  const f32x4 fzero = {0.f, 0.f, 0.f, 0.f};
  f32x4 acc[4][4];
  #pragma unroll
  for (int i = 0; i < 4; ++i)
    #pragma unroll
    for (int j = 0; j < 4; ++j) acc[i][j] = fzero;

  // staging map: wave w stages rows [w*32, w*32+32); lane -> (row=ln>>2, 16B seg=ln&3)
  const int srow = w*32 + (ln >> 2);
  const int seg  = (ln & 3) * 8;
  const u16* ga = A  + (size_t)(tm + srow)*K + seg;
  const u16* gb = Bt + (size_t)(tn + srow)*K + seg;
  u16* lA = As + __builtin_amdgcn_readfirstlane(w * 1024);
  u16* lB = Bs + __builtin_amdgcn_readfirstlane(w * 1024);

  for (int k0 = 0; k0 < K; k0 += 32) {
    gll16(ga + k0,        lA);
    gll16(ga + k0 + 16*K, lA + 512);
    gll16(gb + k0,        lB);
    gll16(gb + k0 + 16*K, lB + 512);
    __syncthreads();
    bf16x8 af[4], bfv[4];
    #pragma unroll
    for (int mi = 0; mi < 4; ++mi)
      af[mi] = *(const bf16x8*)&As[(wr*64 + mi*16 + c)*32 + g*8];
    #pragma unroll
    for (int ni = 0; ni < 4; ++ni)
      bfv[ni] = *(const bf16x8*)&Bs[(wc*64 + ni*16 + c)*32 + g*8];
    #pragma unroll
    for (int mi = 0; mi < 4; ++mi)
      #pragma unroll
      for (int ni = 0; ni < 4; ++ni)
        acc[mi][ni] = __builtin_amdgcn_mfma_f32_16x16x32_bf16(af[mi], bfv[ni], acc[mi][ni], 0, 0, 0);
    __syncthreads();
  }

  // epilogue.  C/D layout: row = g*4 + reg, col = c  (guide §3, m89-verified)
  const int tnw = tn + wc*64;
  float bias_v[4];
  #pragma unroll
  for (int ni = 0; ni < 4; ++ni) bias_v[ni] = bias[tnw + ni*16 + c];

  if (MODE == 1) {
    #pragma unroll
    for (int mi = 0; mi < 4; ++mi)
      #pragma unroll
      for (int r = 0; r < 4; ++r) {
        int mrow = tm + wr*64 + mi*16 + 4*g + r;
        float* op = o0 + (size_t)mrow*768 + tnw + c;
        #pragma unroll
        for (int ni = 0; ni < 4; ++ni)
          op[ni*16] = acc[mi][ni][r] + bias_v[ni];
      }
  } else {
    const int part = tnw / 768;              // 0=q 1=k 2=v (uniform per wave)
    const int hh   = (tnw - part*768) >> 6;  // head (uniform per wave)
    #pragma unroll
    for (int mi = 0; mi < 4; ++mi)
      #pragma unroll
      for (int r = 0; r < 4; ++r) {
        int mrow = tm + wr*64 + mi*16 + 4*g + r;
        int bI = mrow >> 10, s = mrow & 1023;
        size_t base = (((size_t)(bI*12 + hh) << 10) + (size_t)s) * 64 + c;
        #pragma unroll
        for (int ni = 0; ni < 4; ++ni) {
          float v = acc[mi][ni][r] + bias_v[ni];
          size_t idx = base + ni*16;
          if (part == 0)      { qo[idx] = f2bf(v); }
          else if (part == 1) { o0[idx] = v; ko[idx] = f2bf(v); }
          else                { o1[idx] = v; }
        }
      }
  }
}

// ---------- kernel 4: V [B,H,S,64] fp32 (from d_out) -> V^T [B,H,64,S] bf16 ----------
__global__ __launch_bounds__(256)
void transpose_v(const float* __restrict__ vin, u16* __restrict__ vt) {
  __shared__ float t64[64][65];
  const int bh = blockIdx.x, s0 = blockIdx.y * 64;
  const int tr = threadIdx.x >> 4, tc = (threadIdx.x & 15) * 4;
  const float* src = vin + ((size_t)bh*1024 + s0) * 64;
  #pragma unroll
  for (int i = 0; i < 4; ++i) {
    int r = i*16 + tr;                      // r = s offset, tc = dh
    float4 v = *(const float4*)(src + (size_t)r*64 + tc);
    t64[r][tc+0]=v.x; t64[r][tc+1]=v.y; t64[r][tc+2]=v.z; t64[r][tc+3]=v.w;
  }
  __syncthreads();
  u16* dst = vt + (size_t)bh*64*1024 + s0;
  #pragma unroll
  for (int i = 0; i < 4; ++i) {
    int d = i*16 + tr;
    u16x4 ov;
    ov[0]=f2bf(t64[tc+0][d]); ov[1]=f2bf(t64[tc+1][d]);
    ov[2]=f2bf(t64[tc+2][d]); ov[3]=f2bf(t64[tc+3][d]);
    *(u16x4*)(dst + (size_t)d*1024 + tc) = ov;
  }
}

// ---------- kernel 5: causal flash attention, no LDS (K/V are L2-resident) ----------
// Per wave: 16 q-rows.  S^T = mfma(K,Q) so stats live at q = lane&15;
// O^T = mfma(V^T, P) so rescale/divide need no cross-lane broadcast.
__global__ __launch_bounds__(256)
void attn_k(const u16* __restrict__ qb, const u16* __restrict__ kb,
            const u16* __restrict__ vt, u16* __restrict__ attnb)
{
  const int bh = blockIdx.x;
  const int b = bh / 12, h = bh % 12;
  const int w = threadIdx.x >> 6, ln = threadIdx.x & 63;
  const int g = ln >> 4, c = ln & 15;
  const int q0 = blockIdx.y * 64 + w * 16;
  const int q  = q0 + c;
  const size_t hbase = (size_t)bh * 1024 * 64;

  const u16* Qp = qb + hbase + (size_t)(q0 + c) * 64 + g * 8;
  bf16x8 bq0 = *(const bf16x8*)(Qp);
  bf16x8 bq1 = *(const bf16x8*)(Qp + 32);

  const f32x4 fzero = {0.f, 0.f, 0.f, 0.f};
  f32x4 o[4]; o[0]=fzero; o[1]=fzero; o[2]=fzero; o[3]=fzero;
  float m = -1e30f, lsum = 0.f;

  const int ntiles = (q0 + 16 + 31) >> 5;    // keys 0..q0+15, tiles of 32
  for (int kt = 0; kt < ntiles; ++kt) {
    const int k32 = kt * 32;
    const u16* Kp = kb + hbase + (size_t)(k32 + c) * 64 + g * 8;
    bf16x8 ak00 = *(const bf16x8*)(Kp);
    bf16x8 ak01 = *(const bf16x8*)(Kp + 32);
    bf16x8 ak10 = *(const bf16x8*)(Kp + 16*64);
    bf16x8 ak11 = *(const bf16x8*)(Kp + 16*64 + 32);
    f32x4 s0 = fzero, s1 = fzero;           // S^T: row=key(4g+r), col=q(c)
    s0 = __builtin_amdgcn_mfma_f32_16x16x32_bf16(ak00, bq0, s0, 0, 0, 0);
    s0 = __builtin_amdgcn_mfma_f32_16x16x32_bf16(ak01, bq1, s0, 0, 0, 0);
    s1 = __builtin_amdgcn_mfma_f32_16x16x32_bf16(ak10, bq0, s1, 0, 0, 0);
    s1 = __builtin_amdgcn_mfma_f32_16x16x32_bf16(ak11, bq1, s1, 0, 0, 0);

    float x[8];
    #pragma unroll
    for (int t = 0; t < 2; ++t)
      #pragma unroll
      for (int r = 0; r < 4; ++r) {
        int key = k32 + t*16 + 4*g + r;
        float v = (t ? s1[r] : s0[r]) * 0.125f;   // 1/sqrt(64)
        x[t*4+r] = (key <= q) ? v : -1e30f;       // finite sentinel: no inf-inf NaN
      }
    float mt = x[0];
    #pragma unroll
    for (int j = 1; j < 8; ++j) mt = fmaxf(mt, x[j]);
    mt = fmaxf(mt, __shfl_xor(mt, 16));
    mt = fmaxf(mt, __shfl_xor(mt, 32));
    float mn = fmaxf(m, mt);
    float sc = __expf(m - mn);
    float p[8]; float rs = 0.f;
    #pragma unroll
    for (int j = 0; j < 8; ++j) { p[j] = __expf(x[j] - mn); rs += p[j]; }
    rs += __shfl_xor(rs, 16);
    rs += __shfl_xor(rs, 32);
    lsum = lsum * sc + rs;
    m = mn;
    #pragma unroll
    for (int dt = 0; dt < 4; ++dt) o[dt] = o[dt] * sc;

    // build P fragment (B-operand of O^T = V^T * P): lane needs P[q=c][key=8g+j]
    u32 pk00 = pack2(p[0], p[1]);   // keys 4g+{0,1}   (sub-tile 0)
    u32 pk01 = pack2(p[2], p[3]);   // keys 4g+{2,3}
    u32 pk10 = pack2(p[4], p[5]);   // keys 16+4g+{0,1} (sub-tile 1)
    u32 pk11 = pack2(p[6], p[7]);
    const int gp = g & 1;
    const int laneA = (2*gp    )*16 + c;
    const int laneB = (2*gp + 1)*16 + c;
    u32 a0 = (u32)__shfl((int)pk00, laneA), b0 = (u32)__shfl((int)pk10, laneA);
    u32 a1 = (u32)__shfl((int)pk01, laneA), b1 = (u32)__shfl((int)pk11, laneA);
    u32 a2 = (u32)__shfl((int)pk00, laneB), b2 = (u32)__shfl((int)pk10, laneB);
    u32 a3 = (u32)__shfl((int)pk01, laneB), b3 = (u32)__shfl((int)pk11, laneB);
    const bool lo = (g < 2);
    u32x4 pw; pw[0] = lo ? a0 : b0; pw[1] = lo ? a1 : b1;
              pw[2] = lo ? a2 : b2; pw[3] = lo ? a3 : b3;
    bf16x8 pf = __builtin_bit_cast(bf16x8, pw);

    #pragma unroll
    for (int dt = 0; dt < 4; ++dt) {
      bf16x8 av = *(const bf16x8*)(vt + hbase + (size_t)(dt*16 + c)*1024 + k32 + g*8);
      o[dt] = __builtin_amdgcn_mfma_f32_16x16x32_bf16(av, pf, o[dt], 0, 0, 0);
    }
  }

  const float rinv = 1.0f / lsum;
  // O^T layout: lane holds q=c, d = dt*16 + 4g + r  -> attnb[b*1024+q][h*64+d]
  const size_t obase = ((size_t)(b*1024 + q0 + c)) * 768 + h*64;
  #pragma unroll
  for (int dt = 0; dt < 4; ++dt)
    #pragma unroll
    for (int rp = 0; rp < 2; ++rp) {
      u32 pkd = pack2(o[dt][2*rp] * rinv, o[dt][2*rp+1] * rinv);
      *(u32*)(attnb + obase + dt*16 + 4*g + 2*rp) = pkd;
    }
}

// ---------- launch ----------
extern "C" void kernel_launch(void* const* d_in, const int* in_sizes, int n_in,
                              void* d_out, int out_size, void* d_ws, size_t ws_size,
                              hipStream_t stream)
{
  (void)in_sizes; (void)n_in; (void)out_size; (void)ws_size;
  const float* x     = (const float*)d_in[0];
  const float* Wqkv  = (const float*)d_in[1];
  const float* bqkv  = (const float*)d_in[2];
  const float* Wproj = (const float*)d_in[3];
  const float* bproj = (const float*)d_in[4];
  float* out  = (float*)d_out;
  float* outK = out + 6291456;      // [B,H,S,Dh] fp32
  float* outV = out + 2*6291456;

  char* ws = (char*)d_ws;
  u16* xb    = (u16*)ws; ws += 12582912;   // x bf16 [8192][768]
  u16* wqt   = (u16*)ws; ws += 3538944;    // W_qkv^T bf16 [2304][768]
  u16* wpt   = (u16*)ws; ws += 1179648;    // W_proj^T bf16 [768][768]
  u16* qbuf  = (u16*)ws; ws += 12582912;   // Q bf16 [B,H,S,64]
  u16* kbuf  = (u16*)ws; ws += 12582912;   // K bf16 [B,H,S,64]
  u16* vtb   = (u16*)ws; ws += 12582912;   // V^T bf16 [B,H,64,S]
  u16* attnb = (u16*)ws; ws += 12582912;   // attn out bf16 [8192][768]

  cvt_bf16   <<<3072, 256, 0, stream>>>(x, xb, 786432);
  transpose_w<<<dim3(12, 36), 256, 0, stream>>>(Wqkv,  wqt, 768, 2304);
  transpose_w<<<dim3(12, 12), 256, 0, stream>>>(Wproj, wpt, 768, 768);
  gemm_k<0>  <<<dim3(64, 18), 256, 0, stream>>>(xb, wqt, bqkv, outK, outV, qbuf, kbuf);
  transpose_v<<<dim3(96, 16), 256, 0, stream>>>(outV, vtb);
  attn_k     <<<dim3(96, 16), 256, 0, stream>>>(qbuf, kbuf, vtb, attnb);
  gemm_k<1>  <<<dim3(64, 6),  256, 0, stream>>>(attnb, wpt, bproj, out, nullptr, nullptr, nullptr);
}

// Round 2
// 148.997 us; speedup vs baseline: 1.3278x; 1.3278x over previous
//
#include <hip/hip_runtime.h>

typedef unsigned short u16;
typedef unsigned int   u32;
typedef short bf16x8 __attribute__((ext_vector_type(8)));
typedef float f32x4  __attribute__((ext_vector_type(4)));
typedef float f32x16 __attribute__((ext_vector_type(16)));
typedef u16   u16x4  __attribute__((ext_vector_type(4)));
typedef u16   u16x8  __attribute__((ext_vector_type(8)));
typedef u32   u32x2  __attribute__((ext_vector_type(2)));
typedef u32   u32x4  __attribute__((ext_vector_type(4)));

#define DEV __device__ __forceinline__
#define MFMA32(A,B,C) __builtin_amdgcn_mfma_f32_32x32x16_bf16(A,B,C,0,0,0)

// ---------- helpers ----------
DEV u16 f2bf(float f) {                       // fp32 -> bf16 RNE
  u32 u = __builtin_bit_cast(u32, f);
  u32 r = (u + 0x7FFFu + ((u >> 16) & 1u)) >> 16;
  return (u16)r;
}
DEV u32 pack2(float lo, float hi) {
  return (u32)f2bf(lo) | ((u32)f2bf(hi) << 16);
}
DEV void gll16(const u16* g, u16* l) {        // async global->LDS, 16B/lane
  __builtin_amdgcn_global_load_lds((const __attribute__((address_space(1))) u32*)g,
                                   (__attribute__((address_space(3))) u32*)l,
                                   16, 0, 0);
}

// ---------- kernel 1: fp32 -> bf16 convert ----------
__global__ __launch_bounds__(256)
void cvt_bf16(const float* __restrict__ in, u16* __restrict__ out, int n8) {
  int i = blockIdx.x * 256 + threadIdx.x;
  if (i >= n8) return;
  float4 a = ((const float4*)in)[2*i];
  float4 b = ((const float4*)in)[2*i+1];
  u16x8 o;
  o[0]=f2bf(a.x); o[1]=f2bf(a.y); o[2]=f2bf(a.z); o[3]=f2bf(a.w);
  o[4]=f2bf(b.x); o[5]=f2bf(b.y); o[6]=f2bf(b.z); o[7]=f2bf(b.w);
  *(u16x8*)(out + (size_t)i*8) = o;
}

// ---------- kernel 2: W [R][C] fp32 -> W^T [C][R] bf16 ----------
__global__ __launch_bounds__(256)
void transpose_w(const float* __restrict__ in, u16* __restrict__ out, int R, int C) {
  __shared__ float t64[64][65];
  const int r0 = blockIdx.x*64, c0 = blockIdx.y*64;
  const int tr = threadIdx.x >> 4, tc = (threadIdx.x & 15) * 4;
  #pragma unroll
  for (int i = 0; i < 4; ++i) {
    int r = i*16 + tr;
    float4 v = *(const float4*)(in + (size_t)(r0 + r)*C + c0 + tc);
    t64[r][tc+0]=v.x; t64[r][tc+1]=v.y; t64[r][tc+2]=v.z; t64[r][tc+3]=v.w;
  }
  __syncthreads();
  #pragma unroll
  for (int i = 0; i < 4; ++i) {
    int r = i*16 + tr;
    u16x4 ov;
    ov[0]=f2bf(t64[tc+0][r]); ov[1]=f2bf(t64[tc+1][r]);
    ov[2]=f2bf(t64[tc+2][r]); ov[3]=f2bf(t64[tc+3][r]);
    *(u16x4*)(out + (size_t)(c0 + r)*R + r0 + tc) = ov;
  }
}

// ---------- kernel 3/7: bf16 GEMM, m97 structure (128x128 tile, BK=32) ----------
template<int MODE>
__global__ __launch_bounds__(256)
void gemm_k(const u16* __restrict__ A, const u16* __restrict__ Bt,
            const float* __restrict__ bias,
            float* __restrict__ o0, float* __restrict__ o1,
            u16* __restrict__ qo, u16* __restrict__ ko)
{
  constexpr int K = 768;
  __shared__ u16 As[128*32];
  __shared__ u16 Bs[128*32];
  const int tid = threadIdx.x;
  const int w  = tid >> 6, ln = tid & 63;
  const int wr = w >> 1,  wc = w & 1;
  const int g  = ln >> 4, c  = ln & 15;
  const int tm = blockIdx.x * 128, tn = blockIdx.y * 128;

  const f32x4 fzero = {0.f, 0.f, 0.f, 0.f};
  f32x4 acc[4][4];
  #pragma unroll
  for (int i = 0; i < 4; ++i)
    #pragma unroll
    for (int j = 0; j < 4; ++j) acc[i][j] = fzero;

  const int srow = w*32 + (ln >> 2);
  const int seg  = (ln & 3) * 8;
  const u16* ga = A  + (size_t)(tm + srow)*K + seg;
  const u16* gb = Bt + (size_t)(tn + srow)*K + seg;
  u16* lA = As + __builtin_amdgcn_readfirstlane(w * 1024);
  u16* lB = Bs + __builtin_amdgcn_readfirstlane(w * 1024);

  for (int k0 = 0; k0 < K; k0 += 32) {
    gll16(ga + k0,        lA);
    gll16(ga + k0 + 16*K, lA + 512);
    gll16(gb + k0,        lB);
    gll16(gb + k0 + 16*K, lB + 512);
    __syncthreads();
    bf16x8 af[4], bfv[4];
    #pragma unroll
    for (int mi = 0; mi < 4; ++mi)
      af[mi] = *(const bf16x8*)&As[(wr*64 + mi*16 + c)*32 + g*8];
    #pragma unroll
    for (int ni = 0; ni < 4; ++ni)
      bfv[ni] = *(const bf16x8*)&Bs[(wc*64 + ni*16 + c)*32 + g*8];
    #pragma unroll
    for (int mi = 0; mi < 4; ++mi)
      #pragma unroll
      for (int ni = 0; ni < 4; ++ni)
        acc[mi][ni] = __builtin_amdgcn_mfma_f32_16x16x32_bf16(af[mi], bfv[ni], acc[mi][ni], 0, 0, 0);
    __syncthreads();
  }

  const int tnw = tn + wc*64;
  float bias_v[4];
  #pragma unroll
  for (int ni = 0; ni < 4; ++ni) bias_v[ni] = bias[tnw + ni*16 + c];

  if (MODE == 1) {
    #pragma unroll
    for (int mi = 0; mi < 4; ++mi)
      #pragma unroll
      for (int r = 0; r < 4; ++r) {
        int mrow = tm + wr*64 + mi*16 + 4*g + r;
        float* op = o0 + (size_t)mrow*768 + tnw + c;
        #pragma unroll
        for (int ni = 0; ni < 4; ++ni)
          op[ni*16] = acc[mi][ni][r] + bias_v[ni];
      }
  } else {
    const float QSCALE = 0.18033688f;        // 1/sqrt(64) * log2(e), folded into Q
    const int part = tnw / 768;              // 0=q 1=k 2=v (uniform per wave)
    const int hh   = (tnw - part*768) >> 6;
    #pragma unroll
    for (int mi = 0; mi < 4; ++mi)
      #pragma unroll
      for (int r = 0; r < 4; ++r) {
        int mrow = tm + wr*64 + mi*16 + 4*g + r;
        int bI = mrow >> 10, s = mrow & 1023;
        size_t base = (((size_t)(bI*12 + hh) << 10) + (size_t)s) * 64 + c;
        #pragma unroll
        for (int ni = 0; ni < 4; ++ni) {
          float v = acc[mi][ni][r] + bias_v[ni];
          size_t idx = base + ni*16;
          if (part == 0)      { qo[idx] = f2bf(v * QSCALE); }
          else if (part == 1) { o0[idx] = v; ko[idx] = f2bf(v); }
          else                { o1[idx] = v; }
        }
      }
  }
}

// ---------- kernel 4: V [B,H,S,64] fp32 -> V^T [B,H,64,S] bf16 ----------
__global__ __launch_bounds__(256)
void transpose_v(const float* __restrict__ vin, u16* __restrict__ vt) {
  __shared__ float t64[64][65];
  const int bh = blockIdx.x, s0 = blockIdx.y * 64;
  const int tr = threadIdx.x >> 4, tc = (threadIdx.x & 15) * 4;
  const float* src = vin + ((size_t)bh*1024 + s0) * 64;
  #pragma unroll
  for (int i = 0; i < 4; ++i) {
    int r = i*16 + tr;
    float4 v = *(const float4*)(src + (size_t)r*64 + tc);
    t64[r][tc+0]=v.x; t64[r][tc+1]=v.y; t64[r][tc+2]=v.z; t64[r][tc+3]=v.w;
  }
  __syncthreads();
  u16* dst = vt + (size_t)bh*64*1024 + s0;
  #pragma unroll
  for (int i = 0; i < 4; ++i) {
    int d = i*16 + tr;
    u16x4 ov;
    ov[0]=f2bf(t64[tc+0][d]); ov[1]=f2bf(t64[tc+1][d]);
    ov[2]=f2bf(t64[tc+2][d]); ov[3]=f2bf(t64[tc+3][d]);
    *(u16x4*)(dst + (size_t)d*1024 + tc) = ov;
  }
}

// ---------- kernel 5: causal flash attention, 32x32 swapped-QK^T ----------
// Per wave: 32 q rows. S^T = mfma(K,Q): lane owns q=lane&31, 16 keys across regs.
// O^T = mfma(V^T, P): same col=q, so all softmax state is lane-local.
// Work units heavy-first: u -> head=u%96, qt=31-u/96.

#define LOADT(KF, VF, TI) do {                                              \
  const int k32_ = (TI) << 5;                                               \
  const u16* kp_ = kb + hbase + (size_t)(k32_ + cl) * 64 + (hf << 3);       \
  KF[0] = *(const bf16x8*)(kp_);       KF[1] = *(const bf16x8*)(kp_ + 16);  \
  KF[2] = *(const bf16x8*)(kp_ + 32);  KF[3] = *(const bf16x8*)(kp_ + 48);  \
  const u16* vp_ = vt + hbase + (size_t)cl * 1024 + k32_ + (hf << 3);       \
  VF[0] = *(const bf16x8*)(vp_);           VF[1] = *(const bf16x8*)(vp_ + 16); \
  VF[2] = *(const bf16x8*)(vp_ + 32768);   VF[3] = *(const bf16x8*)(vp_ + 32768 + 16); \
} while (0)

#define TILE(KF, VF, DIAG) do {                                             \
  f32x16 st_ = 0.f;                                                         \
  st_ = MFMA32(KF[0], qf[0], st_); st_ = MFMA32(KF[1], qf[1], st_);         \
  st_ = MFMA32(KF[2], qf[2], st_); st_ = MFMA32(KF[3], qf[3], st_);         \
  float x_[16];                                                             \
  _Pragma("unroll")                                                         \
  for (int r = 0; r < 16; ++r) x_[r] = st_[r];                              \
  if (DIAG) {                                                               \
    _Pragma("unroll")                                                       \
    for (int r = 0; r < 16; ++r)                                            \
      if (((r & 3) + 8 * (r >> 2) + (hf << 2)) > cl) x_[r] = -1e30f;        \
  }                                                                         \
  float y_[8];                                                              \
  _Pragma("unroll")                                                         \
  for (int r = 0; r < 8; ++r) y_[r] = fmaxf(x_[r], x_[r + 8]);              \
  _Pragma("unroll")                                                         \
  for (int r = 0; r < 4; ++r) y_[r] = fmaxf(y_[r], y_[r + 4]);              \
  float mt_ = fmaxf(fmaxf(y_[0], y_[1]), fmaxf(y_[2], y_[3]));              \
  mt_ = fmaxf(mt_, __shfl_xor(mt_, 32));                                    \
  if (!__all(mt_ - m <= 8.0f)) {         /* T13 defer-max */                \
    float mn_ = fmaxf(m, mt_);                                              \
    float sc_ = exp2f(m - mn_);                                             \
    _Pragma("unroll")                                                       \
    for (int r = 0; r < 16; ++r) { o0[r] *= sc_; o1[r] *= sc_; }            \
    lsum *= sc_; m = mn_;                                                   \
  }                                                                         \
  float p_[16]; float rs_ = 0.f;                                            \
  _Pragma("unroll")                                                         \
  for (int r = 0; r < 16; ++r) { p_[r] = exp2f(x_[r] - m); rs_ += p_[r]; }  \
  rs_ += __shfl_xor(rs_, 32);                                               \
  lsum += rs_;                                                              \
  u32 ww_[8], xw_[8];                                                       \
  _Pragma("unroll")                                                         \
  for (int i = 0; i < 8; ++i) ww_[i] = pack2(p_[2*i], p_[2*i+1]);           \
  _Pragma("unroll")                                                         \
  for (int i = 0; i < 8; ++i) xw_[i] = (u32)__shfl_xor((int)ww_[i], 32);    \
  u32x4 b0_, b1_;                                                           \
  b0_[0] = hf ? xw_[2] : ww_[0]; b0_[1] = hf ? xw_[3] : ww_[1];             \
  b0_[2] = hf ? ww_[2] : xw_[0]; b0_[3] = hf ? ww_[3] : xw_[1];             \
  b1_[0] = hf ? xw_[6] : ww_[4]; b1_[1] = hf ? xw_[7] : ww_[5];             \
  b1_[2] = hf ? ww_[6] : xw_[4]; b1_[3] = hf ? ww_[7] : xw_[5];             \
  bf16x8 pb0_ = __builtin_bit_cast(bf16x8, b0_);                            \
  bf16x8 pb1_ = __builtin_bit_cast(bf16x8, b1_);                            \
  o0 = MFMA32(VF[0], pb0_, o0); o0 = MFMA32(VF[1], pb1_, o0);               \
  o1 = MFMA32(VF[2], pb0_, o1); o1 = MFMA32(VF[3], pb1_, o1);               \
} while (0)

__global__ __launch_bounds__(256)
void attn_k(const u16* __restrict__ qb, const u16* __restrict__ kb,
            const u16* __restrict__ vt, u16* __restrict__ attnb)
{
  const int w = threadIdx.x >> 6, ln = threadIdx.x & 63;
  const int u = blockIdx.x * 4 + w;
  const int head = u % 96;
  const int qt = 31 - (u / 96);          // heaviest q-tiles scheduled first
  const int q0 = qt << 5;
  const int b = head / 12, h = head % 12;
  const int cl = ln & 31, hf = ln >> 5;
  const size_t hbase = (size_t)head << 16;

  // Q fragments (B-operand): k-dim d = ds*16 + hf*8 + j, col q = cl
  const u16* Qp = qb + hbase + (size_t)(q0 + cl) * 64 + (hf << 3);
  bf16x8 qf[4];
  qf[0] = *(const bf16x8*)(Qp);       qf[1] = *(const bf16x8*)(Qp + 16);
  qf[2] = *(const bf16x8*)(Qp + 32);  qf[3] = *(const bf16x8*)(Qp + 48);

  f32x16 o0 = 0.f, o1 = 0.f;
  float m = -1e30f, lsum = 0.f;

  bf16x8 kA[4], vA[4], kB[4], vB[4];
  const int nfull = qt;                  // full (unmasked) 32-key tiles
  LOADT(kA, vA, 0);
  int t = 0;
  while (t < nfull) {
    LOADT(kB, vB, t + 1);                // prefetch next tile into other buffer
    TILE(kA, vA, 0);
    ++t;
    if (t >= nfull) break;
    LOADT(kA, vA, t + 1);
    TILE(kB, vB, 0);
    ++t;
  }
  if (nfull & 1) TILE(kB, vB, 1);        // diagonal (masked) tile
  else           TILE(kA, vA, 1);

  const float rinv = 1.0f / lsum;
  // O^T: lane holds q=cl, d = (r&3) + 8*(r>>2) + 4*hf (+32 for o1)
  const size_t obase = ((size_t)(b * 1024 + q0 + cl)) * 768 + h * 64;
  #pragma unroll
  for (int grp = 0; grp < 4; ++grp) {
    u32x2 s0, s1;
    s0[0] = pack2(o0[grp*4+0]*rinv, o0[grp*4+1]*rinv);
    s0[1] = pack2(o0[grp*4+2]*rinv, o0[grp*4+3]*rinv);
    *(u32x2*)(attnb + obase + grp*8 + (hf << 2)) = s0;
    s1[0] = pack2(o1[grp*4+0]*rinv, o1[grp*4+1]*rinv);
    s1[1] = pack2(o1[grp*4+2]*rinv, o1[grp*4+3]*rinv);
    *(u32x2*)(attnb + obase + 32 + grp*8 + (hf << 2)) = s1;
  }
}

// ---------- launch ----------
extern "C" void kernel_launch(void* const* d_in, const int* in_sizes, int n_in,
                              void* d_out, int out_size, void* d_ws, size_t ws_size,
                              hipStream_t stream)
{
  (void)in_sizes; (void)n_in; (void)out_size; (void)ws_size;
  const float* x     = (const float*)d_in[0];
  const float* Wqkv  = (const float*)d_in[1];
  const float* bqkv  = (const float*)d_in[2];
  const float* Wproj = (const float*)d_in[3];
  const float* bproj = (const float*)d_in[4];
  float* out  = (float*)d_out;
  float* outK = out + 6291456;      // [B,H,S,Dh] fp32
  float* outV = out + 2*6291456;

  char* ws = (char*)d_ws;
  u16* xb    = (u16*)ws; ws += 12582912;   // x bf16 [8192][768]
  u16* wqt   = (u16*)ws; ws += 3538944;    // W_qkv^T bf16 [2304][768]
  u16* wpt   = (u16*)ws; ws += 1179648;    // W_proj^T bf16 [768][768]
  u16* qbuf  = (u16*)ws; ws += 12582912;   // Q bf16 (pre-scaled) [B,H,S,64]
  u16* kbuf  = (u16*)ws; ws += 12582912;   // K bf16 [B,H,S,64]
  u16* vtb   = (u16*)ws; ws += 12582912;   // V^T bf16 [B,H,64,S]
  u16* attnb = (u16*)ws; ws += 12582912;   // attn out bf16 [8192][768]

  cvt_bf16   <<<3072, 256, 0, stream>>>(x, xb, 786432);
  transpose_w<<<dim3(12, 36), 256, 0, stream>>>(Wqkv,  wqt, 768, 2304);
  transpose_w<<<dim3(12, 12), 256, 0, stream>>>(Wproj, wpt, 768, 768);
  gemm_k<0>  <<<dim3(64, 18), 256, 0, stream>>>(xb, wqt, bqkv, outK, outV, qbuf, kbuf);
  transpose_v<<<dim3(96, 16), 256, 0, stream>>>(outV, vtb);
  attn_k     <<<768, 256, 0, stream>>>(qbuf, kbuf, vtb, attnb);
  gemm_k<1>  <<<dim3(64, 6),  256, 0, stream>>>(attnb, wpt, bproj, out, nullptr, nullptr, nullptr);
}